// Round 19
// baseline (8664.471 us; speedup 1.0000x reference)
//
#include <hip/hip_runtime.h>
#include <hip/hip_bf16.h>
#include <stdint.h>
#include <stddef.h>
#include <math.h>

#define HH 512
#define TT 512
#define BB 32
#define XH 3072   // 6*H
#define GH 2560   // 5*H
#define NWG 32    // unit-partition WGs per group
#define UPW 16    // units per WG
#define NGRP 2    // row-groups
#define RPG 16    // rows per group
#define KCH 16    // k chunks of 32
#define HSK 520   // hs kc-chunk stride in shorts (bank-spread)
#define POISON64 0xFFFFFFFFFFFFFFFFULL
#define SCOPE __HIP_MEMORY_SCOPE_AGENT

typedef __attribute__((ext_vector_type(8))) short bf16x8;
typedef __attribute__((ext_vector_type(4))) float f32x4;
typedef unsigned long long u64;

__device__ __forceinline__ float bf2f(unsigned short u){
  union{float f; unsigned int i;} v; v.i = ((unsigned int)u)<<16; return v.f;
}
__device__ __forceinline__ unsigned short f2bf(float f){
  union{float f; unsigned int i;} v; v.f=f;
  unsigned int x=v.i;
  return (unsigned short)((x + 0x7FFFu + ((x>>16)&1u))>>16);
}
__device__ __forceinline__ float sigm(float x){ return 1.f/(1.f+__expf(-x)); }
__device__ __forceinline__ float tanh_f(float x){ return 1.f - 2.f/(__expf(2.f*x)+1.f); }

__global__ void fill_sentinel_f(float* out, int n, float v){
  int i = blockIdx.x*blockDim.x + threadIdx.x;
  int stride = gridDim.x*blockDim.x;
  for (; i < n; i += stride) out[i] = v;
}

__global__ void conv_f2bf(const float* __restrict__ in, unsigned short* __restrict__ out, int n){
  int i = (blockIdx.x*blockDim.x + threadIdx.x)*4;
  int stride = gridDim.x*blockDim.x*4;
  for (; i < n; i += stride){
    float4 v = *(const float4*)(in + i);
    ushort4 o; o.x=f2bf(v.x); o.y=f2bf(v.y); o.z=f2bf(v.z); o.w=f2bf(v.w);
    *(ushort4*)(out + i) = o;
  }
}

// ------- MFMA bf16 GEMM: C_bf16[M,N] = A_bf16[M,K] @ Bt_bf16[N,K]^T + bias ---
#define BM 128
#define BN 128
#define BKK 32

__global__ __launch_bounds__(256)
void gemm_bt(const unsigned short* __restrict__ A, const unsigned short* __restrict__ Bt,
             const float* __restrict__ bias, unsigned short* __restrict__ C,
             int M, int N, int K)
{
  __shared__ unsigned short Alds[BM*BKK];
  __shared__ unsigned short Blds[BN*BKK];
  const int tid = threadIdx.x;
  const int lane = tid & 63;
  const int w = tid >> 6;
  const int gm = blockIdx.y, gn = blockIdx.x;
  const int wm = (w>>1)*64, wn = (w&1)*64;
  const int l15 = lane & 15, l4 = lane >> 4;
  f32x4 acc[4][4] = {};
  for (int k0 = 0; k0 < K; k0 += BKK){
    __syncthreads();
    #pragma unroll
    for (int it = 0; it < 2; ++it){
      int id2 = it*256 + tid;
      int row = id2 >> 2, kc = (id2 & 3)*8;
      *(bf16x8*)&Alds[row*BKK + kc] = *(const bf16x8*)(A + (size_t)(gm*BM+row)*K + k0 + kc);
      *(bf16x8*)&Blds[row*BKK + kc] = *(const bf16x8*)(Bt + (size_t)(gn*BN+row)*K + k0 + kc);
    }
    __syncthreads();
    bf16x8 af[4], bfv[4];
    #pragma unroll
    for (int i=0;i<4;i++) af[i]  = *(const bf16x8*)&Alds[(wm + i*16 + l15)*BKK + l4*8];
    #pragma unroll
    for (int j=0;j<4;j++) bfv[j] = *(const bf16x8*)&Blds[(wn + j*16 + l15)*BKK + l4*8];
    #pragma unroll
    for (int i=0;i<4;i++)
      #pragma unroll
      for (int j=0;j<4;j++)
        acc[i][j] = __builtin_amdgcn_mfma_f32_16x16x32_bf16(af[i], bfv[j], acc[i][j], 0,0,0);
  }
  #pragma unroll
  for (int i=0;i<4;i++){
    int row0 = gm*BM + wm + i*16 + l4*4;
    #pragma unroll
    for (int j=0;j<4;j++){
      int col = gn*BN + wn + j*16 + l15;
      float bz = bias[col];
      #pragma unroll
      for (int r=0;r<4;r++)
        C[(size_t)(row0+r)*N + col] = f2bf(acc[i][j][r] + bz);
    }
  }
}

// ---- scan v11: data-as-sync (poison chunks), no flags, no acquires ----------
__global__ __launch_bounds__(512)
void lstm_scan_v11(const unsigned short* __restrict__ xp, // [T*B][6H] bf16
                   const float* __restrict__ whh,         // [5H][H] f32
                   const float* __restrict__ masks,       // [T*B] f32
                   unsigned short* __restrict__ ab,       // [T*B][H] bf16, poisoned
                   float* __restrict__ outF,              // [T*B][H] f32 or null
                   float* __restrict__ hT_out, float* __restrict__ cT_out,
                   int reverse)
{
  __shared__ __align__(16) unsigned short hs[KCH*HSK];   // 16.6 KB
  __shared__ float pre[5][RPG][17];                      // 5.4 KB
  __shared__ unsigned short xps[2][6][RPG][16];          // 6 KB
  __shared__ float mlds[2][RPG];
  __shared__ __align__(8) unsigned short pwl[RPG*16];

  const int gid = blockIdx.x & 1;
  const int wgi = blockIdx.x >> 1;
  const int tid = threadIdx.x, wv = tid >> 6, lane = tid & 63;
  const int l15 = lane & 15, l4 = lane >> 4;
  const int u0 = wgi*UPW;
  const int r0 = gid*RPG;

  // dot waves: B fragments (hi+lo split bf16), loaded once
  bf16x8 Bhi[KCH], Blo[KCH];
  if (wv < 5){
    const float* wrow = whh + ((size_t)(wv*HH + u0 + l15))*HH + l4*8;
    #pragma unroll
    for (int kc = 0; kc < KCH; ++kc){
      float4 v0 = *(const float4*)(wrow + kc*32);
      float4 v1 = *(const float4*)(wrow + kc*32 + 4);
      float vv[8] = {v0.x,v0.y,v0.z,v0.w,v1.x,v1.y,v1.z,v1.w};
      bf16x8 hh, ll;
      #pragma unroll
      for (int j = 0; j < 8; ++j){
        unsigned short hb = f2bf(vv[j]);
        hh[j] = (short)hb;
        ll[j] = (short)f2bf(vv[j] - bf2f(hb));
      }
      Bhi[kc] = hh; Blo[kc] = ll;
    }
  }

  // prologue: wave6 stages xps[0]/mask for t0
  if (wv == 6){
    const int t0 = reverse ? (TT-1) : 0;
    #pragma unroll
    for (int it = 0; it < 3; ++it){
      int p = it*64 + lane;            // 192 pieces
      int half = p & 1, pg = p >> 1;   // pg 0..95
      int g = pg % 6, row = pg / 6;
      *(uint4*)&xps[0][g][row][half*8] =
        *(const uint4*)(xp + ((size_t)t0*BB + r0 + row)*XH + g*HH + u0 + half*8);
    }
    if (lane < RPG) mlds[0][lane] = masks[t0*BB + r0 + lane];
  }

  const int r4 = lane >> 4, uu = lane & 15;
  float c_st[4] = {0,0,0,0}, h_st[4] = {0,0,0,0};
  __syncthreads();   // xps[0] ready

  for (int s = 0; s < TT; ++s){
    const int t = reverse ? (TT-1-s) : s;
    if (s > 0){
      // stage h(t_prev): 2048 u64 chunks, 4/thread; poll value until non-poison
      const int tp = reverse ? (t+1) : (t-1);
      const u64* src = (const u64*)(ab + ((size_t)tp*BB + r0)*HH);
      u64 v[4];
      #pragma unroll
      for (int it = 0; it < 4; ++it)
        v[it] = __hip_atomic_load(&src[it*512 + tid], __ATOMIC_RELAXED, SCOPE);
      int rounds = 0;
      for (;;){
        bool bad = false;
        #pragma unroll
        for (int it = 0; it < 4; ++it){
          if (v[it] == POISON64){
            v[it] = __hip_atomic_load(&src[it*512 + tid], __ATOMIC_RELAXED, SCOPE);
            bad = true;
          }
        }
        if (!bad) break;
        if (++rounds > 2) __builtin_amdgcn_s_sleep(1);   // immediate retry first
      }
      #pragma unroll
      for (int it = 0; it < 4; ++it){
        int j = it*512 + tid;
        int r = j >> 7, ww = j & 127;
        int kc = ww >> 3, q4 = (ww >> 1) & 3, half = ww & 1;
        *(u64*)&hs[kc*HSK + (q4*16 + r)*8 + half*4] = v[it];
      }
    }
    __syncthreads();   // hs + xps[s&1] ready
    if (s > 0 && wv < 5){
      f32x4 a1 = {0.f,0.f,0.f,0.f}, a2 = {0.f,0.f,0.f,0.f};
      #pragma unroll
      for (int kc = 0; kc < KCH; ++kc){
        bf16x8 A = *(const bf16x8*)&hs[kc*HSK + lane*8];
        a1 = __builtin_amdgcn_mfma_f32_16x16x32_bf16(A, Bhi[kc], a1, 0,0,0);
        a2 = __builtin_amdgcn_mfma_f32_16x16x32_bf16(A, Blo[kc], a2, 0,0,0);
      }
      #pragma unroll
      for (int r = 0; r < 4; ++r) pre[wv][l4*4 + r][l15] = a1[r] + a2[r];
    }
    if (wv == 6 && s+1 < TT){
      const int t1 = reverse ? (t-1) : (t+1);
      const int nb = (s+1) & 1;
      #pragma unroll
      for (int it = 0; it < 3; ++it){
        int p = it*64 + lane;
        int half = p & 1, pg = p >> 1;
        int g = pg % 6, row = pg / 6;
        *(uint4*)&xps[nb][g][row][half*8] =
          *(const uint4*)(xp + ((size_t)t1*BB + r0 + row)*XH + g*HH + u0 + half*8);
      }
      if (lane < RPG) mlds[nb][lane] = masks[t1*BB + r0 + lane];
    }
    __syncthreads();   // pre + xps[(s+1)&1] ready
    if (wv == 5){
      const int sb = s & 1;
      float hvals[4];
      #pragma unroll
      for (int i = 0; i < 4; ++i){
        const int row = r4 + i*4;
        float p0=0,p1=0,p2=0,p3=0,p4=0;
        if (s > 0){
          p0 = pre[0][row][uu]; p1 = pre[1][row][uu]; p2 = pre[2][row][uu];
          p3 = pre[3][row][uu]; p4 = pre[4][row][uu];
        }
        float xi = bf2f(xps[sb][0][row][uu]);
        float xf = bf2f(xps[sb][1][row][uu]);
        float xo = bf2f(xps[sb][2][row][uu]);
        float xg = bf2f(xps[sb][3][row][uu]);
        float xj = bf2f(xps[sb][4][row][uu]);
        float xk = bf2f(xps[sb][5][row][uu]);
        float mm = mlds[sb][row];
        float ig = sigm(p0 + xi);
        float fg = sigm(p1 + xf + 1.0f);
        float og = sigm(p2 + xo);
        float tg = sigm(p3 + xg);
        float jg = tanh_f(p4 + xj);
        float cn = fg*c_st[i] + ig*jg;
        cn = mm*cn + (1.f-mm)*c_st[i];
        float hn = tg*og*tanh_f(cn) + (1.f-tg)*xk;
        hn = mm*hn + (1.f-mm)*h_st[i];
        c_st[i] = cn; h_st[i] = hn;
        hvals[i] = hn;
        pwl[row*16 + uu] = f2bf(hn);
      }
      __threadfence_block();
      {
        // publish 16 u64 chunks; each 8B store is atomic -> self-announcing
        int row = lane >> 2, q = lane & 3;
        u64 v = *(const u64*)&pwl[row*16 + q*4];
        u64* dstp = (u64*)(ab + ((size_t)t*BB + r0 + row)*HH + u0 + q*4);
        __hip_atomic_store(dstp, v, __ATOMIC_RELAXED, SCOPE);
      }
      if (outF){
        #pragma unroll
        for (int i = 0; i < 4; ++i)
          outF[((size_t)t*BB + r0 + r4 + i*4)*HH + u0 + uu] = hvals[i];
      }
    }
  }
  if (wv == 5){
    #pragma unroll
    for (int i = 0; i < 4; ++i){
      int row = r0 + r4 + i*4;
      hT_out[(size_t)row*HH + u0 + uu] = h_st[i];
      cT_out[(size_t)row*HH + u0 + uu] = c_st[i];
    }
  }
}

// ------------------------------- launch ---------------------------------------
extern "C" void kernel_launch(void* const* d_in, const int* in_sizes, int n_in,
                              void* d_out, int out_size, void* d_ws, size_t ws_size,
                              hipStream_t stream)
{
  const float* x = nullptr; const float* masks = nullptr;
  const float* wih[4] = {}; const float* bih[4] = {}; const float* whh[4] = {};
  int nw = 0, nb = 0, nh = 0;
  for (int i = 0; i < n_in; ++i){
    const int sz = in_sizes[i];
    const float* p = (const float*)d_in[i];
    if      (sz == TT*BB*HH){ if (!x) x = p; }
    else if (sz == TT*BB)   { if (!masks) masks = p; }
    else if (sz == XH*HH)   { if (nw < 4) wih[nw++] = p; }
    else if (sz == XH)      { if (nb < 4) bih[nb++] = p; }
    else if (sz == GH*HH)   { if (nh < 4) whh[nh++] = p; }
  }
  float* out = (float*)d_out;
  if (!x || !masks || nw != 4 || nb != 4 || nh != 4){
    fill_sentinel_f<<<512, 256, 0, stream>>>(out, out_size, 777.0f);
    return;
  }

  char* ws = (char*)d_ws;
  size_t off = 0;
  auto alloc = [&](size_t bytes)->void*{
    void* p = ws + off; off += (bytes + 255) & ~(size_t)255; return p;
  };
  unsigned short* xbf   = (unsigned short*)alloc((size_t)TT*BB*HH*2);  // 16.8 MB
  unsigned short* ab0   = (unsigned short*)alloc((size_t)TT*BB*HH*2);  // 16.8 MB
  unsigned short* ab1   = (unsigned short*)alloc((size_t)TT*BB*HH*2);  // 16.8 MB
  unsigned short* wbf   = (unsigned short*)alloc((size_t)XH*HH*2);     //  3.1 MB
  unsigned short* xproj = (unsigned short*)alloc((size_t)TT*BB*XH*2);  // 50.3 MB

  const int thr = 256;
  auto cgrid = [&](int n){ int g = (n/4 + thr - 1)/thr; return g > 2048 ? 2048 : g; };
  conv_f2bf<<<cgrid(TT*BB*HH), thr, 0, stream>>>(x, xbf, TT*BB*HH);

  float* hn = out + (size_t)TT*BB*HH;
  float* cn = hn + (size_t)4*BB*HH;

  unsigned short* ab[2] = {ab0, ab1};

  for (int L = 0; L < 4; ++L){
    const int rev = L & 1;
    unsigned short* cur  = ab[L & 1];
    const unsigned short* prev = (L == 0) ? xbf : ab[(L+1) & 1];
    conv_f2bf<<<cgrid(XH*HH), thr, 0, stream>>>(wih[L], wbf, XH*HH);
    gemm_bt<<<dim3(XH/BN, (TT*BB)/BM), 256, 0, stream>>>(
        prev, wbf, bih[L], xproj, TT*BB, XH, HH);
    // poison h-exchange buffer: 0xFF bytes = bf16 NaN chunks (unreachable)
    (void)hipMemsetAsync(cur, 0xFF, (size_t)TT*BB*HH*2, stream);

    lstm_scan_v11<<<NGRP*NWG, 512, 0, stream>>>(
        xproj, whh[L], masks, cur,
        (L == 3) ? out : nullptr,
        hn + (size_t)L*BB*HH, cn + (size_t)L*BB*HH,
        rev);
  }
}

// Round 20
// 7871.466 us; speedup vs baseline: 1.1007x; 1.1007x over previous
//
#include <hip/hip_runtime.h>
#include <hip/hip_bf16.h>
#include <stdint.h>
#include <stddef.h>
#include <math.h>

#define HH 512
#define TT 512
#define BB 32
#define XH 3072   // 6*H
#define GH 2560   // 5*H
#define NWG 32    // unit-partition WGs per group
#define UPW 16    // units per WG
#define NGRP 2    // row-groups
#define RPG 16    // rows per group
#define KCH 16    // k chunks of 32
#define HSK 520   // hs kc-chunk stride in shorts (bank-spread)
#define POISON64 0xFFFFFFFFFFFFFFFFULL
#define SCOPE __HIP_MEMORY_SCOPE_AGENT
#define WGSC  __HIP_MEMORY_SCOPE_WORKGROUP

typedef __attribute__((ext_vector_type(8))) short bf16x8;
typedef __attribute__((ext_vector_type(4))) float f32x4;
typedef unsigned long long u64;

__device__ __forceinline__ float bf2f(unsigned short u){
  union{float f; unsigned int i;} v; v.i = ((unsigned int)u)<<16; return v.f;
}
__device__ __forceinline__ unsigned short f2bf(float f){
  union{float f; unsigned int i;} v; v.f=f;
  unsigned int x=v.i;
  return (unsigned short)((x + 0x7FFFu + ((x>>16)&1u))>>16);
}
__device__ __forceinline__ float sigm(float x){ return 1.f/(1.f+__expf(-x)); }
__device__ __forceinline__ float tanh_f(float x){ return 1.f - 2.f/(__expf(2.f*x)+1.f); }

__global__ void fill_sentinel_f(float* out, int n, float v){
  int i = blockIdx.x*blockDim.x + threadIdx.x;
  int stride = gridDim.x*blockDim.x;
  for (; i < n; i += stride) out[i] = v;
}

__global__ void conv_f2bf(const float* __restrict__ in, unsigned short* __restrict__ out, int n){
  int i = (blockIdx.x*blockDim.x + threadIdx.x)*4;
  int stride = gridDim.x*blockDim.x*4;
  for (; i < n; i += stride){
    float4 v = *(const float4*)(in + i);
    ushort4 o; o.x=f2bf(v.x); o.y=f2bf(v.y); o.z=f2bf(v.z); o.w=f2bf(v.w);
    *(ushort4*)(out + i) = o;
  }
}

// ------- MFMA bf16 GEMM: C_bf16[M,N] = A_bf16[M,K] @ Bt_bf16[N,K]^T + bias ---
#define BM 128
#define BN 128
#define BKK 32

__global__ __launch_bounds__(256)
void gemm_bt(const unsigned short* __restrict__ A, const unsigned short* __restrict__ Bt,
             const float* __restrict__ bias, unsigned short* __restrict__ C,
             int M, int N, int K)
{
  __shared__ unsigned short Alds[BM*BKK];
  __shared__ unsigned short Blds[BN*BKK];
  const int tid = threadIdx.x;
  const int lane = tid & 63;
  const int w = tid >> 6;
  const int gm = blockIdx.y, gn = blockIdx.x;
  const int wm = (w>>1)*64, wn = (w&1)*64;
  const int l15 = lane & 15, l4 = lane >> 4;
  f32x4 acc[4][4] = {};
  for (int k0 = 0; k0 < K; k0 += BKK){
    __syncthreads();
    #pragma unroll
    for (int it = 0; it < 2; ++it){
      int id2 = it*256 + tid;
      int row = id2 >> 2, kc = (id2 & 3)*8;
      *(bf16x8*)&Alds[row*BKK + kc] = *(const bf16x8*)(A + (size_t)(gm*BM+row)*K + k0 + kc);
      *(bf16x8*)&Blds[row*BKK + kc] = *(const bf16x8*)(Bt + (size_t)(gn*BN+row)*K + k0 + kc);
    }
    __syncthreads();
    bf16x8 af[4], bfv[4];
    #pragma unroll
    for (int i=0;i<4;i++) af[i]  = *(const bf16x8*)&Alds[(wm + i*16 + l15)*BKK + l4*8];
    #pragma unroll
    for (int j=0;j<4;j++) bfv[j] = *(const bf16x8*)&Blds[(wn + j*16 + l15)*BKK + l4*8];
    #pragma unroll
    for (int i=0;i<4;i++)
      #pragma unroll
      for (int j=0;j<4;j++)
        acc[i][j] = __builtin_amdgcn_mfma_f32_16x16x32_bf16(af[i], bfv[j], acc[i][j], 0,0,0);
  }
  #pragma unroll
  for (int i=0;i<4;i++){
    int row0 = gm*BM + wm + i*16 + l4*4;
    #pragma unroll
    for (int j=0;j<4;j++){
      int col = gn*BN + wn + j*16 + l15;
      float bz = bias[col];
      #pragma unroll
      for (int r=0;r<4;r++)
        C[(size_t)(row0+r)*N + col] = f2bf(acc[i][j][r] + bz);
    }
  }
}

// ---- scan v12: flag-gated (issue-order) + poison-validated UC staging -------
__global__ __launch_bounds__(512)
void lstm_scan_v12(const unsigned short* __restrict__ xp, // [T*B][6H] bf16
                   const float* __restrict__ whh,         // [5H][H] f32
                   const float* __restrict__ masks,       // [T*B] f32
                   unsigned short* __restrict__ ab,       // [T*B][H] bf16, poisoned
                   float* __restrict__ outF,              // [T*B][H] f32 or null
                   float* __restrict__ hT_out, float* __restrict__ cT_out,
                   int* __restrict__ flags,               // [NGRP][NWG][16] zeroed
                   int reverse)
{
  __shared__ __align__(16) unsigned short hs[KCH*HSK];   // 16.6 KB
  __shared__ float pre[5][RPG][17];                      // 5.4 KB
  __shared__ unsigned short xps[2][6][RPG][16];          // 6 KB
  __shared__ float mlds[2][RPG];
  __shared__ __align__(8) unsigned short pwl[RPG*16];
  __shared__ int go_l;

  const int gid = blockIdx.x & 1;
  const int wgi = blockIdx.x >> 1;
  const int tid = threadIdx.x, wv = tid >> 6, lane = tid & 63;
  const int l15 = lane & 15, l4 = lane >> 4;
  const int u0 = wgi*UPW;
  const int r0 = gid*RPG;
  int* gflags = flags + gid*NWG*16;
  int* myflag = gflags + wgi*16;

  if (tid == 0) go_l = 0;

  // dot waves: B fragments (hi+lo split bf16), loaded once
  bf16x8 Bhi[KCH], Blo[KCH];
  if (wv < 5){
    const float* wrow = whh + ((size_t)(wv*HH + u0 + l15))*HH + l4*8;
    #pragma unroll
    for (int kc = 0; kc < KCH; ++kc){
      float4 v0 = *(const float4*)(wrow + kc*32);
      float4 v1 = *(const float4*)(wrow + kc*32 + 4);
      float vv[8] = {v0.x,v0.y,v0.z,v0.w,v1.x,v1.y,v1.z,v1.w};
      bf16x8 hh, ll;
      #pragma unroll
      for (int j = 0; j < 8; ++j){
        unsigned short hb = f2bf(vv[j]);
        hh[j] = (short)hb;
        ll[j] = (short)f2bf(vv[j] - bf2f(hb));
      }
      Bhi[kc] = hh; Blo[kc] = ll;
    }
  }

  // prologue: wave6 stages xps[0]/mask for t0
  if (wv == 6){
    const int t0 = reverse ? (TT-1) : 0;
    #pragma unroll
    for (int it = 0; it < 3; ++it){
      int p = it*64 + lane;            // 192 pieces
      int half = p & 1, pg = p >> 1;   // pg 0..95
      int g = pg % 6, row = pg / 6;
      *(uint4*)&xps[0][g][row][half*8] =
        *(const uint4*)(xp + ((size_t)t0*BB + r0 + row)*XH + g*HH + u0 + half*8);
    }
    if (lane < RPG) mlds[0][lane] = masks[t0*BB + r0 + lane];
  }

  const int r4 = lane >> 4, uu = lane & 15;
  float c_st[4] = {0,0,0,0}, h_st[4] = {0,0,0,0};
  __syncthreads();   // go_l init + xps[0]

  for (int s = 0; s < TT; ++s){
    const int t = reverse ? (TT-1-s) : s;
    if (s > 0){
      // gate: wave7 polls 32 producer flags (low-traffic)
      if (wv == 7){
        for (;;){
          int v = (lane < NWG)
            ? __hip_atomic_load(gflags + lane*16, __ATOMIC_RELAXED, SCOPE) : s;
          if (__all(v >= s)) break;
          __builtin_amdgcn_s_sleep(1);
        }
        if (lane == 0) __hip_atomic_store(&go_l, s, __ATOMIC_RELAXED, WGSC);
      } else {
        while (__hip_atomic_load(&go_l, __ATOMIC_RELAXED, WGSC) < s){}
      }
      // stage h(t_prev): UC 8B loads, poison-validated (flag = issue-order only)
      const int tp = reverse ? (t+1) : (t-1);
      const u64* src = (const u64*)(ab + ((size_t)tp*BB + r0)*HH);
      u64 v[4];
      #pragma unroll
      for (int it = 0; it < 4; ++it)
        v[it] = __hip_atomic_load(&src[it*512 + tid], __ATOMIC_RELAXED, SCOPE);
      int rounds = 0;
      for (;;){
        bool bad = false;
        #pragma unroll
        for (int it = 0; it < 4; ++it){
          if (v[it] == POISON64){
            v[it] = __hip_atomic_load(&src[it*512 + tid], __ATOMIC_RELAXED, SCOPE);
            bad = true;
          }
        }
        if (!bad) break;
        if (++rounds > 2) __builtin_amdgcn_s_sleep(1);
      }
      #pragma unroll
      for (int it = 0; it < 4; ++it){
        int j = it*512 + tid;
        int r = j >> 7, ww = j & 127;
        int kc = ww >> 3, q4 = (ww >> 1) & 3, half = ww & 1;
        *(u64*)&hs[kc*HSK + (q4*16 + r)*8 + half*4] = v[it];
      }
    }
    __syncthreads();   // hs + xps[s&1] ready
    if (s > 0 && wv < 5){
      f32x4 a1 = {0.f,0.f,0.f,0.f}, a2 = {0.f,0.f,0.f,0.f};
      #pragma unroll
      for (int kc = 0; kc < KCH; ++kc){
        bf16x8 A = *(const bf16x8*)&hs[kc*HSK + lane*8];
        a1 = __builtin_amdgcn_mfma_f32_16x16x32_bf16(A, Bhi[kc], a1, 0,0,0);
        a2 = __builtin_amdgcn_mfma_f32_16x16x32_bf16(A, Blo[kc], a2, 0,0,0);
      }
      #pragma unroll
      for (int r = 0; r < 4; ++r) pre[wv][l4*4 + r][l15] = a1[r] + a2[r];
    }
    if (wv == 6 && s+1 < TT){
      const int t1 = reverse ? (t-1) : (t+1);
      const int nb = (s+1) & 1;
      #pragma unroll
      for (int it = 0; it < 3; ++it){
        int p = it*64 + lane;
        int half = p & 1, pg = p >> 1;
        int g = pg % 6, row = pg / 6;
        *(uint4*)&xps[nb][g][row][half*8] =
          *(const uint4*)(xp + ((size_t)t1*BB + r0 + row)*XH + g*HH + u0 + half*8);
      }
      if (lane < RPG) mlds[nb][lane] = masks[t1*BB + r0 + lane];
    }
    __syncthreads();   // pre + xps[(s+1)&1] ready
    if (wv == 5){
      const int sb = s & 1;
      float hvals[4];
      #pragma unroll
      for (int i = 0; i < 4; ++i){
        const int row = r4 + i*4;
        float p0=0,p1=0,p2=0,p3=0,p4=0;
        if (s > 0){
          p0 = pre[0][row][uu]; p1 = pre[1][row][uu]; p2 = pre[2][row][uu];
          p3 = pre[3][row][uu]; p4 = pre[4][row][uu];
        }
        float xi = bf2f(xps[sb][0][row][uu]);
        float xf = bf2f(xps[sb][1][row][uu]);
        float xo = bf2f(xps[sb][2][row][uu]);
        float xg = bf2f(xps[sb][3][row][uu]);
        float xj = bf2f(xps[sb][4][row][uu]);
        float xk = bf2f(xps[sb][5][row][uu]);
        float mm = mlds[sb][row];
        float ig = sigm(p0 + xi);
        float fg = sigm(p1 + xf + 1.0f);
        float og = sigm(p2 + xo);
        float tg = sigm(p3 + xg);
        float jg = tanh_f(p4 + xj);
        float cn = fg*c_st[i] + ig*jg;
        cn = mm*cn + (1.f-mm)*c_st[i];
        float hn = tg*og*tanh_f(cn) + (1.f-tg)*xk;
        hn = mm*hn + (1.f-mm)*h_st[i];
        c_st[i] = cn; h_st[i] = hn;
        hvals[i] = hn;
        pwl[row*16 + uu] = f2bf(hn);
      }
      __threadfence_block();
      {
        // publish 16 u64 chunks (UC, self-complete by 8B atomicity)
        int row = lane >> 2, q = lane & 3;
        u64 v = *(const u64*)&pwl[row*16 + q*4];
        u64* dstp = (u64*)(ab + ((size_t)t*BB + r0 + row)*HH + u0 + q*4);
        __hip_atomic_store(dstp, v, __ATOMIC_RELAXED, SCOPE);
      }
      // flag immediately (issue order); consumers poison-validate the data
      if (lane == 0)
        __hip_atomic_store(myflag, s+1, __ATOMIC_RELAXED, SCOPE);
      if (outF){
        #pragma unroll
        for (int i = 0; i < 4; ++i)
          outF[((size_t)t*BB + r0 + r4 + i*4)*HH + u0 + uu] = hvals[i];
      }
    }
  }
  if (wv == 5){
    #pragma unroll
    for (int i = 0; i < 4; ++i){
      int row = r0 + r4 + i*4;
      hT_out[(size_t)row*HH + u0 + uu] = h_st[i];
      cT_out[(size_t)row*HH + u0 + uu] = c_st[i];
    }
  }
}

// ------------------------------- launch ---------------------------------------
extern "C" void kernel_launch(void* const* d_in, const int* in_sizes, int n_in,
                              void* d_out, int out_size, void* d_ws, size_t ws_size,
                              hipStream_t stream)
{
  const float* x = nullptr; const float* masks = nullptr;
  const float* wih[4] = {}; const float* bih[4] = {}; const float* whh[4] = {};
  int nw = 0, nb = 0, nh = 0;
  for (int i = 0; i < n_in; ++i){
    const int sz = in_sizes[i];
    const float* p = (const float*)d_in[i];
    if      (sz == TT*BB*HH){ if (!x) x = p; }
    else if (sz == TT*BB)   { if (!masks) masks = p; }
    else if (sz == XH*HH)   { if (nw < 4) wih[nw++] = p; }
    else if (sz == XH)      { if (nb < 4) bih[nb++] = p; }
    else if (sz == GH*HH)   { if (nh < 4) whh[nh++] = p; }
  }
  float* out = (float*)d_out;
  if (!x || !masks || nw != 4 || nb != 4 || nh != 4){
    fill_sentinel_f<<<512, 256, 0, stream>>>(out, out_size, 777.0f);
    return;
  }

  char* ws = (char*)d_ws;
  size_t off = 0;
  auto alloc = [&](size_t bytes)->void*{
    void* p = ws + off; off += (bytes + 255) & ~(size_t)255; return p;
  };
  unsigned short* xbf   = (unsigned short*)alloc((size_t)TT*BB*HH*2);  // 16.8 MB
  unsigned short* ab0   = (unsigned short*)alloc((size_t)TT*BB*HH*2);  // 16.8 MB
  unsigned short* ab1   = (unsigned short*)alloc((size_t)TT*BB*HH*2);  // 16.8 MB
  unsigned short* wbf   = (unsigned short*)alloc((size_t)XH*HH*2);     //  3.1 MB
  unsigned short* xproj = (unsigned short*)alloc((size_t)TT*BB*XH*2);  // 50.3 MB
  int*            flags = (int*)alloc((size_t)4*NGRP*NWG*16*4);        //  16 KB

  (void)hipMemsetAsync(flags, 0, (size_t)4*NGRP*NWG*16*4, stream);

  const int thr = 256;
  auto cgrid = [&](int n){ int g = (n/4 + thr - 1)/thr; return g > 2048 ? 2048 : g; };
  conv_f2bf<<<cgrid(TT*BB*HH), thr, 0, stream>>>(x, xbf, TT*BB*HH);

  float* hn = out + (size_t)TT*BB*HH;
  float* cn = hn + (size_t)4*BB*HH;

  unsigned short* ab[2] = {ab0, ab1};

  for (int L = 0; L < 4; ++L){
    const int rev = L & 1;
    unsigned short* cur  = ab[L & 1];
    const unsigned short* prev = (L == 0) ? xbf : ab[(L+1) & 1];
    conv_f2bf<<<cgrid(XH*HH), thr, 0, stream>>>(wih[L], wbf, XH*HH);
    gemm_bt<<<dim3(XH/BN, (TT*BB)/BM), 256, 0, stream>>>(
        prev, wbf, bih[L], xproj, TT*BB, XH, HH);
    // poison h-exchange buffer: 0xFF bytes = bf16 NaN chunks (unreachable)
    (void)hipMemsetAsync(cur, 0xFF, (size_t)TT*BB*HH*2, stream);

    lstm_scan_v12<<<NGRP*NWG, 512, 0, stream>>>(
        xproj, whh[L], masks, cur,
        (L == 3) ? out : nullptr,
        hn + (size_t)L*BB*HH, cn + (size_t)L*BB*HH,
        flags + (size_t)L*NGRP*NWG*16,
        rev);
  }
}